// Round 13
// baseline (196.454 us; speedup 1.0000x reference)
//
#include <hip/hip_runtime.h>

// ---------------------------------------------------------------------------
// GalerkinAttention on MI355X (gfx950), round 12 = r10 champion +
//   (1) k1: 2-deep A-prefetch (pA/pB named reg sets, loop unrolled x2;
//       vmcnt(8) ledger keeps A(t+2) in flight a FULL iteration)
//   (2) preduce fused into k3a (one 32-block kernel, dd-loop)
// k4 / k3b / cvt_w identical to r10.
//
// Shapes: B=4, N=8192, D=512, H=8, Dh=64. Algebra: y = x @ M_b^T + b_out,
//   M_b[d'][d] = sum_h W_out[d',h-blk] . P_bh . W_q[h-blk,d] / n
//
// MFMA 16x16x32 bf16 (verified r1-11):
//   A frag: lane l holds A[row=l&15][k = ks*32 + (l>>4)*8 + e]
//   B frag: lane l holds B[col=l&15][same k]
//   C/D   : lane l reg r -> C[row=(l>>4)*4+r][col=l&15]
// LDS swizzle (8-short XOR, PMC-verified 0 conflicts):
//   stage src col pre-swizzled ((l&7)^(l>>3))*8; read col ^ ((c16&7)<<3)
// k1 vmcnt ledger (per thread, FIFO):
//   steady iter t: entry outstanding = A(t+1):8. issue gB(t):4 ->
//   [A(t+1):8, gB:4]; cvt reads arrived set (compiler wait vmcnt(12),
//   satisfied); issue A(t+2):8 -> 20 outstanding; vmcnt(8) drains
//   A(t+1)+gB, leaves A(t+2). Tail t=6,7: vmcnt(0).
// ---------------------------------------------------------------------------

typedef __attribute__((ext_vector_type(8))) short bf16x8;
typedef __attribute__((ext_vector_type(4))) float f32x4;
typedef __attribute__((ext_vector_type(4))) unsigned short u16x4;
typedef __attribute__((ext_vector_type(4))) unsigned int u32x4;

__device__ __forceinline__ unsigned short f2bf(float f) {
  unsigned int u = __builtin_bit_cast(unsigned int, f);
  u += 0x7FFFu + ((u >> 16) & 1u);   // RNE
  return (unsigned short)(u >> 16);
}

__device__ __forceinline__ unsigned int cvt2(float lo, float hi) {
  return ((unsigned int)f2bf(hi) << 16) | (unsigned int)f2bf(lo);
}

__device__ __forceinline__ f32x4 mfma16(bf16x8 a, bf16x8 b, f32x4 c) {
  return __builtin_amdgcn_mfma_f32_16x16x32_bf16(a, b, c, 0, 0, 0);
}

__device__ __forceinline__ void gload16(const void* g, void* l) {
  __builtin_amdgcn_global_load_lds(
      (const __attribute__((address_space(1))) void*)g,
      (__attribute__((address_space(3))) void*)l, 16, 0, 0);
}

// ------------------------ K0: convert weights (merged) ----------------------
__global__ void k_cvt_w(const float* __restrict__ Wqkv,
                        const float* __restrict__ Wout,
                        unsigned short* __restrict__ Wb,
                        unsigned short* __restrict__ Wob) {
  int i = blockIdx.x * 256 + threadIdx.x;
  const float4* src;
  u16x4* dst;
  if (i < 196608) { src = (const float4*)Wqkv + i; dst = (u16x4*)Wb + i; }
  else { i -= 196608; src = (const float4*)Wout + i; dst = (u16x4*)Wob + i; }
  float4 v = *src;
  u16x4 o;
  o[0] = f2bf(v.x); o[1] = f2bf(v.y); o[2] = f2bf(v.z); o[3] = f2bf(v.w);
  *dst = o;
}

// ---------------- K1: kv GEMM (2-deep A-prefetch) + LN + P ------------------
// 1D grid 2048 (XCD-swizzled): wgid=(bid&7)*256+(bid>>3); rt=wgid>>3, h=wgid&7
__launch_bounds__(256, 3)
__global__ void k1_kvp(const float* __restrict__ x,
                       const unsigned short* __restrict__ wqkvb,
                       const float* __restrict__ gK, const float* __restrict__ bK,
                       const float* __restrict__ gV, const float* __restrict__ bV,
                       float* __restrict__ Ppart) {
  __shared__ __align__(16) unsigned short As[8192];   // 16 KB
  __shared__ __align__(16) unsigned short Bs[8192];   // 16 KB
  const int bid = (int)blockIdx.x;
  const int wgid = (bid & 7) * 256 + (bid >> 3);      // bijective (2048%8==0)
  const int rt = wgid >> 3, h = wgid & 7;
  const int tid = (int)threadIdx.x;
  const int l = tid & 63, w = tid >> 6;
  const int wr = w >> 1, wc = w & 1;
  const int g = l >> 4, c16 = l & 15;
  const int row0 = rt * 128;
  const int swz = ((l & 7) ^ (l >> 3)) * 8;

  const float* gx = x + (size_t)(row0 + w * 32 + (l >> 3)) * 512 + swz;
  const int bcol = (w < 2) ? (512 + h * 64 + w * 32) : (1024 + h * 64 + (w - 2) * 32);
  const unsigned short* gsB = wqkvb + (bcol + (l >> 3)) * 512 + swz;
  unsigned short* la = As + w * 2048 + l * 8;

  f32x4 acc[4][4] = {};
  float4 pA[8], pB[8];   // constant-indexed only (unrolled) -> registers

#define LOAD_PF(PF, T)                                                  \
  {                                                                     \
    _Pragma("unroll")                                                   \
    for (int j = 0; j < 4; ++j) {                                       \
      PF[2 * j]     = *(const float4*)(gx + (T) * 64 + j * 4096);       \
      PF[2 * j + 1] = *(const float4*)(gx + (T) * 64 + j * 4096 + 4);   \
    }                                                                   \
  }
#define CVT_WRITE(PF)                                                   \
  {                                                                     \
    _Pragma("unroll")                                                   \
    for (int j = 0; j < 4; ++j) {                                       \
      u32x4 c;                                                          \
      c[0] = cvt2(PF[2 * j].x, PF[2 * j].y);                            \
      c[1] = cvt2(PF[2 * j].z, PF[2 * j].w);                            \
      c[2] = cvt2(PF[2 * j + 1].x, PF[2 * j + 1].y);                    \
      c[3] = cvt2(PF[2 * j + 1].z, PF[2 * j + 1].w);                    \
      *(u32x4*)(la + j * 512) = c;                                      \
    }                                                                   \
  }
#define STAGE_B(T)                                                      \
  {                                                                     \
    _Pragma("unroll")                                                   \
    for (int j = 0; j < 4; ++j)                                         \
      gload16(gsB + (T) * 64 + j * 8 * 512, Bs + w * 2048 + j * 512);   \
  }
#define COMPUTE()                                                       \
  {                                                                     \
    _Pragma("unroll")                                                   \
    for (int ks = 0; ks < 2; ++ks) {                                    \
      const int kcol = (ks * 32 + g * 8) ^ ((c16 & 7) << 3);            \
      bf16x8 af[4], bfv[4];                                             \
      _Pragma("unroll")                                                 \
      for (int mi = 0; mi < 4; ++mi)                                    \
        af[mi] = *(const bf16x8*)&As[(wr * 64 + mi * 16 + c16) * 64 + kcol]; \
      _Pragma("unroll")                                                 \
      for (int ni = 0; ni < 4; ++ni)                                    \
        bfv[ni] = *(const bf16x8*)&Bs[(wc * 64 + ni * 16 + c16) * 64 + kcol]; \
      _Pragma("unroll")                                                 \
      for (int mi = 0; mi < 4; ++mi)                                    \
        _Pragma("unroll")                                               \
        for (int ni = 0; ni < 4; ++ni)                                  \
          acc[mi][ni] = mfma16(af[mi], bfv[ni], acc[mi][ni]);           \
    }                                                                   \
  }

  // prologue: A(0) -> pA, A(1) -> pB
  LOAD_PF(pA, 0);
  LOAD_PF(pB, 1);

#pragma unroll
  for (int p = 0; p < 4; ++p) {
    // ======== even tile t = 2p (data in pA; prefetch A(t+2) -> pA) =========
    {
      const int t = 2 * p;
      STAGE_B(t);
      CVT_WRITE(pA);
      __builtin_amdgcn_sched_barrier(0);
      if (p < 3) {
        LOAD_PF(pA, t + 2);
        __builtin_amdgcn_sched_barrier(0);
        asm volatile("s_waitcnt vmcnt(8) lgkmcnt(0)" ::: "memory");
      } else {
        asm volatile("s_waitcnt vmcnt(0) lgkmcnt(0)" ::: "memory");
      }
      __builtin_amdgcn_sched_barrier(0);
      __builtin_amdgcn_s_barrier();
      COMPUTE();
      __builtin_amdgcn_sched_barrier(0);
      __builtin_amdgcn_s_barrier();
    }
    // ======== odd tile t = 2p+1 (data in pB; prefetch A(t+2) -> pB) ========
    {
      const int t = 2 * p + 1;
      STAGE_B(t);
      CVT_WRITE(pB);
      __builtin_amdgcn_sched_barrier(0);
      if (p < 3) {
        LOAD_PF(pB, t + 2);
        __builtin_amdgcn_sched_barrier(0);
        asm volatile("s_waitcnt vmcnt(8) lgkmcnt(0)" ::: "memory");
      } else {
        asm volatile("s_waitcnt vmcnt(0) lgkmcnt(0)" ::: "memory");
      }
      __builtin_amdgcn_sched_barrier(0);
      __builtin_amdgcn_s_barrier();
      COMPUTE();
      __builtin_amdgcn_sched_barrier(0);
      __builtin_amdgcn_s_barrier();
    }
  }
#undef LOAD_PF
#undef CVT_WRITE
#undef STAGE_B
#undef COMPUTE

  // ---- per-head LayerNorm (wave col-half: wc=0 -> k, wc=1 -> v)
  const float* gamma = (wc == 0) ? gK : gV;
  const float* beta  = (wc == 0) ? bK : bV;
  float gm[4], bt[4];
#pragma unroll
  for (int ni = 0; ni < 4; ++ni) {
    gm[ni] = gamma[h * 64 + ni * 16 + c16];
    bt[ni] = beta[h * 64 + ni * 16 + c16];
  }
  unsigned short* dst = (wc == 0) ? As : Bs;
#pragma unroll
  for (int mi = 0; mi < 4; ++mi) {
    float mean4[4], rs4[4];
#pragma unroll
    for (int r = 0; r < 4; ++r) {
      float a0 = acc[mi][0][r], a1 = acc[mi][1][r];
      float a2 = acc[mi][2][r], a3 = acc[mi][3][r];
      float s1 = a0 + a1 + a2 + a3;
      float s2 = a0 * a0 + a1 * a1 + a2 * a2 + a3 * a3;
#pragma unroll
      for (int m = 1; m <= 8; m <<= 1) {   // reduce over 16-lane col group
        s1 += __shfl_xor(s1, m, 64);
        s2 += __shfl_xor(s2, m, 64);
      }
      const float mean = s1 * (1.0f / 64.0f);
      const float var = s2 * (1.0f / 64.0f) - mean * mean;
      mean4[r] = mean;
      rs4[r] = rsqrtf(var + 1e-5f);
    }
    const int n0 = wr * 64 + mi * 16 + g * 4;
#pragma unroll
    for (int ni = 0; ni < 4; ++ni) {
      u16x4 o;
#pragma unroll
      for (int r = 0; r < 4; ++r)
        o[r] = f2bf((acc[mi][ni][r] - mean4[r]) * rs4[r] * gm[ni] + bt[ni]);
      // phys8 = (n>>3) ^ (d&15); d&15 == c16
      *(u16x4*)&dst[(ni * 16 + c16) * 128 + (((n0 >> 3) ^ c16) << 3) + (n0 & 7)] = o;
    }
  }
  __syncthreads();

  // ---- P-partial: wave w covers dh rows w*16..w*16+15, all 64 dv, n=128
  f32x4 pacc[4] = {};
#pragma unroll
  for (int ks = 0; ks < 4; ++ks) {
    const int grp = ((ks * 4 + g) ^ c16) << 3;
    bf16x8 af = *(const bf16x8*)&As[(w * 16 + c16) * 128 + grp];
#pragma unroll
    for (int ni = 0; ni < 4; ++ni) {
      bf16x8 bv = *(const bf16x8*)&Bs[(ni * 16 + c16) * 128 + grp];
      pacc[ni] = mfma16(af, bv, pacc[ni]);
    }
  }
  const int bh = (rt >> 6) * 8 + h;
  float* Pp = Ppart + ((size_t)(bh * 64 + (rt & 63))) * 4096;
#pragma unroll
  for (int ni = 0; ni < 4; ++ni)
#pragma unroll
    for (int r = 0; r < 4; ++r)
      Pp[(w * 16 + g * 4 + r) * 64 + ni * 16 + c16] = pacc[ni][r];
}

// ------ K3a (fused reduce): Gt[b][d][h*64+dv] from Ppart directly -----------
// grid 32 (one block per bh), 256 threads; reduce 64 slabs -> Pl, then all 8
// d-blocks. Gt[b][d][h*64+dv] = sum_dh P[bh][dh][dv] * Wqkv[h*64+dh][d]/8192
__launch_bounds__(256)
__global__ void k3a_g(const float* __restrict__ Wqkv,
                      const float* __restrict__ Ppart,
                      unsigned short* __restrict__ Gt) {
  __shared__ float Pl[4096];
  const int bh = blockIdx.x;
  const int b = bh >> 3, h = bh & 7;
  const int t = (int)threadIdx.x;

  // reduce: thread t sums float4 lanes {t, t+256, t+512, t+768} over 64 slabs
  float4 a0 = {0, 0, 0, 0}, a1 = a0, a2 = a0, a3 = a0;
  const float* base = Ppart + (size_t)bh * 262144;
  for (int sl = 0; sl < 64; ++sl) {
    const float4* p = (const float4*)(base + sl * 4096);
    float4 v0 = p[t], v1 = p[t + 256], v2 = p[t + 512], v3 = p[t + 768];
    a0.x += v0.x; a0.y += v0.y; a0.z += v0.z; a0.w += v0.w;
    a1.x += v1.x; a1.y += v1.y; a1.z += v1.z; a1.w += v1.w;
    a2.x += v2.x; a2.y += v2.y; a2.z += v2.z; a2.w += v2.w;
    a3.x += v3.x; a3.y += v3.y; a3.z += v3.z; a3.w += v3.w;
  }
  ((float4*)Pl)[t] = a0;
  ((float4*)Pl)[t + 256] = a1;
  ((float4*)Pl)[t + 512] = a2;
  ((float4*)Pl)[t + 768] = a3;
  __syncthreads();

  const int qg = t >> 6, dl = t & 63;
  for (int dd = 0; dd < 8; ++dd) {
    const int d = dd * 64 + dl;
    float acc[16] = {};
    for (int dh = 0; dh < 64; ++dh) {
      const float wq = Wqkv[(h * 64 + dh) * 512 + d];
      const float* pr = &Pl[dh * 64 + qg * 16];
#pragma unroll
      for (int i = 0; i < 16; ++i) acc[i] += pr[i] * wq;
    }
    unsigned short* go = &Gt[(b * 512 + d) * 512 + h * 64 + qg * 16];
#pragma unroll
    for (int i = 0; i < 16; ++i) go[i] = f2bf(acc[i] * (1.0f / 8192.0f));
  }
}

// ----------------------- 128^2 single-buffer GEMM pieces --------------------
__device__ __forceinline__ void stage_tile(const unsigned short* pa,
                                           const unsigned short* pb,
                                           unsigned short* As, unsigned short* Bs,
                                           int w) {
#pragma unroll
  for (int j = 0; j < 4; ++j) {
    gload16(pa + j * 8 * 512, As + w * 2048 + j * 512);
    gload16(pb + j * 8 * 512, Bs + w * 2048 + j * 512);
  }
}

__device__ __forceinline__ void compute_tile(const unsigned short* As,
                                             const unsigned short* Bs,
                                             int wr, int wc, int g, int c16,
                                             f32x4 acc[4][4]) {
#pragma unroll
  for (int ks = 0; ks < 2; ++ks) {
    const int kcol = (ks * 32 + g * 8) ^ ((c16 & 7) << 3);
    bf16x8 af[4], bfv[4];
#pragma unroll
    for (int mi = 0; mi < 4; ++mi)
      af[mi] = *(const bf16x8*)&As[(wr * 64 + mi * 16 + c16) * 64 + kcol];
#pragma unroll
    for (int ni = 0; ni < 4; ++ni)
      bfv[ni] = *(const bf16x8*)&Bs[(wc * 64 + ni * 16 + c16) * 64 + kcol];
#pragma unroll
    for (int mi = 0; mi < 4; ++mi)
#pragma unroll
      for (int ni = 0; ni < 4; ++ni)
        acc[mi][ni] = mfma16(af[mi], bfv[ni], acc[mi][ni]);
  }
}

// ----------- K3b: M_b[d'][d] = sum_e Wout[d'][e] * Gt_b[d][e] ---------------
__launch_bounds__(256)
__global__ void k3b_m(const unsigned short* __restrict__ wob,
                      const unsigned short* __restrict__ Gt,
                      unsigned short* __restrict__ Mb) {
  __shared__ __align__(16) unsigned short As[8192];
  __shared__ __align__(16) unsigned short Bs[8192];
  const int rt = blockIdx.x, ct = blockIdx.y, b = blockIdx.z;
  const int tid = (int)threadIdx.x;
  const int l = tid & 63, w = tid >> 6;
  const int wr = w >> 1, wc = w & 1;
  const int g = l >> 4, c16 = l & 15;
  const int row0 = rt * 128, col0 = ct * 128;
  const int swz = ((l & 7) ^ (l >> 3)) * 8;

  const unsigned short* gsA = wob + (row0 + w * 32 + (l >> 3)) * 512 + swz;
  const unsigned short* gsB = Gt + b * 262144 + (col0 + w * 32 + (l >> 3)) * 512 + swz;

  f32x4 acc[4][4] = {};
  for (int kt = 0; kt < 8; ++kt) {
    stage_tile(gsA + kt * 64, gsB + kt * 64, As, Bs, w);
    __syncthreads();
    compute_tile(As, Bs, wr, wc, g, c16, acc);
    __syncthreads();
  }

#pragma unroll
  for (int mi = 0; mi < 4; ++mi)
#pragma unroll
    for (int ni = 0; ni < 4; ++ni) {
      const int colg = col0 + wc * 64 + ni * 16 + c16;
#pragma unroll
      for (int r = 0; r < 4; ++r) {
        const int rowg = row0 + wr * 64 + mi * 16 + g * 4 + r;
        Mb[(b * 512 + rowg) * 512 + colg] = f2bf(acc[mi][ni][r]);
      }
    }
}

// ---------------- K4: y = x @ M_b^T + b_out (A reg-staged f32) --------------
// 1D grid 1024 (XCD-swizzled): wgid=(bid&7)*128+(bid>>3); rt=wgid>>2, ct=wgid&3
__launch_bounds__(256, 3)
__global__ void k4_final(const float* __restrict__ x,
                         const unsigned short* __restrict__ Mb,
                         const float* __restrict__ bout,
                         float* __restrict__ y) {
  __shared__ __align__(16) unsigned short As[8192];
  __shared__ __align__(16) unsigned short Bs[8192];
  const int bid = (int)blockIdx.x;
  const int wgid = (bid & 7) * 128 + (bid >> 3);      // bijective (1024%8==0)
  const int rt = wgid >> 2, ct = wgid & 3;
  const int tid = (int)threadIdx.x;
  const int l = tid & 63, w = tid >> 6;
  const int wr = w >> 1, wc = w & 1;
  const int g = l >> 4, c16 = l & 15;
  const int row0 = rt * 128, col0 = ct * 128;
  const int bb = row0 >> 13;
  const int swz = ((l & 7) ^ (l >> 3)) * 8;

  const float* gx = x + (size_t)(row0 + w * 32 + (l >> 3)) * 512 + swz;
  const unsigned short* gsB =
      Mb + (size_t)bb * 262144 + (col0 + w * 32 + (l >> 3)) * 512 + swz;
  unsigned short* la = As + w * 2048 + l * 8;

  f32x4 acc[4][4] = {};
  float4 pf[8];
#pragma unroll
  for (int j = 0; j < 4; ++j) {
    pf[2 * j]     = *(const float4*)(gx + j * 4096);
    pf[2 * j + 1] = *(const float4*)(gx + j * 4096 + 4);
  }

  for (int kt = 0; kt < 8; ++kt) {
#pragma unroll
    for (int j = 0; j < 4; ++j) {
      u32x4 c;
      c[0] = cvt2(pf[2 * j].x, pf[2 * j].y);
      c[1] = cvt2(pf[2 * j].z, pf[2 * j].w);
      c[2] = cvt2(pf[2 * j + 1].x, pf[2 * j + 1].y);
      c[3] = cvt2(pf[2 * j + 1].z, pf[2 * j + 1].w);
      *(u32x4*)(la + j * 512) = c;
    }
#pragma unroll
    for (int j = 0; j < 4; ++j)
      gload16(gsB + kt * 64 + j * 8 * 512, Bs + w * 2048 + j * 512);
    __builtin_amdgcn_sched_barrier(0);
    if (kt < 7) {
#pragma unroll
      for (int j = 0; j < 4; ++j) {
        pf[2 * j]     = *(const float4*)(gx + (kt + 1) * 64 + j * 4096);
        pf[2 * j + 1] = *(const float4*)(gx + (kt + 1) * 64 + j * 4096 + 4);
      }
      asm volatile("s_waitcnt vmcnt(8) lgkmcnt(0)" ::: "memory");
    } else {
      asm volatile("s_waitcnt vmcnt(0) lgkmcnt(0)" ::: "memory");
    }
    __builtin_amdgcn_sched_barrier(0);
    __builtin_amdgcn_s_barrier();
#pragma unroll
    for (int ks = 0; ks < 2; ++ks) {
      const int kcol = (ks * 32 + g * 8) ^ ((c16 & 7) << 3);
      bf16x8 af[4], bfv[4];
#pragma unroll
      for (int mi = 0; mi < 4; ++mi)
        af[mi] = *(const bf16x8*)&As[(wr * 64 + mi * 16 + c16) * 64 + kcol];
#pragma unroll
      for (int ni = 0; ni < 4; ++ni)
        bfv[ni] = *(const bf16x8*)&Bs[(wc * 64 + ni * 16 + c16) * 64 + kcol];
#pragma unroll
      for (int mi = 0; mi < 4; ++mi)
#pragma unroll
        for (int ni = 0; ni < 4; ++ni)
          acc[mi][ni] = mfma16(af[mi], bfv[ni], acc[mi][ni]);
    }
    __builtin_amdgcn_sched_barrier(0);
    __builtin_amdgcn_s_barrier();
  }

  float bo[4];
#pragma unroll
  for (int ni = 0; ni < 4; ++ni)
    bo[ni] = bout[col0 + wc * 64 + ni * 16 + c16];
#pragma unroll
  for (int mi = 0; mi < 4; ++mi)
#pragma unroll
    for (int ni = 0; ni < 4; ++ni) {
      const int colg = col0 + wc * 64 + ni * 16 + c16;
#pragma unroll
      for (int r = 0; r < 4; ++r) {
        const int rowg = row0 + wr * 64 + mi * 16 + g * 4 + r;
        y[rowg * 512 + colg] = acc[mi][ni][r] + bo[ni];
      }
    }
}

// ---------------------------------------------------------------------------
extern "C" void kernel_launch(void* const* d_in, const int* in_sizes, int n_in,
                              void* d_out, int out_size, void* d_ws, size_t ws_size,
                              hipStream_t stream) {
  (void)in_sizes; (void)n_in; (void)out_size; (void)ws_size;
  const float* x    = (const float*)d_in[0];
  const float* Wqkv = (const float*)d_in[1];
  const float* gK   = (const float*)d_in[2];
  const float* bK   = (const float*)d_in[3];
  const float* gV   = (const float*)d_in[4];
  const float* bV   = (const float*)d_in[5];
  const float* Wout = (const float*)d_in[6];
  const float* bout = (const float*)d_in[7];
  float* y = (float*)d_out;

  // workspace carve (~40 MB)
  char* w = (char*)d_ws;
  unsigned short* Wb    = (unsigned short*)(w);             //  1,572,864
  unsigned short* Wob   = (unsigned short*)(w + 1572864);   //    524,288
  unsigned short* Gt    = (unsigned short*)(w + 2097152);   //  2,097,152
  unsigned short* Mb    = (unsigned short*)(w + 4194304);   //  2,097,152
  float*          Ppart = (float*)         (w + 6291456);   // 33,554,432

  k_cvt_w<<<1024, 256, 0, stream>>>(Wqkv, Wout, Wb, Wob);

  k1_kvp<<<2048, 256, 0, stream>>>(x, Wb, gK, bK, gV, bV, Ppart);
  k3a_g<<<32, 256, 0, stream>>>(Wqkv, Ppart, Gt);
  k3b_m<<<dim3(4, 4, 4), 256, 0, stream>>>(Wob, Gt, Mb);
  k4_final<<<1024, 256, 0, stream>>>(x, Mb, bout, y);
}

// Round 14
// 174.111 us; speedup vs baseline: 1.1283x; 1.1283x over previous
//
#include <hip/hip_runtime.h>

// ---------------------------------------------------------------------------
// GalerkinAttention on MI355X (gfx950), round 14 = r10 champion (127.3us)
// + r12's fused k3a (preduce dispatch deleted). NOTHING else changed.
// r13 lesson: 2-deep prefetch spilled to scratch (WRITE_SIZE 33->81MB,
// VGPR capped 84) -> reverted to r10's 1-deep.
//
// Shapes: B=4, N=8192, D=512, H=8, Dh=64. Algebra: y = x @ M_b^T + b_out,
//   M_b[d'][d] = sum_h W_out[d',h-blk] . P_bh . W_q[h-blk,d] / n
//
// Pipeline:
//   K0 : convert W_qkv, W_out to bf16 (merged)
//   K1 : per (128-row-tile, head): kv = x @ W^T; A reg-staged from f32
//        (1-deep prefetch), B via global_load_lds; 32KB LDS, 2 barriers/kt;
//        epilogue: in-register LN -> kn/vn to LDS (16B-XOR transpose) ->
//        P-partial MFMA -> plain stores to Ppart (no atomics)
//   K3a: fused: P[bh] = sum_slab Ppart (LDS) then
//        Gt[b][d][h*64+dv] = sum_dh P[bh][dh][dv] * Wqkv[h*64+dh][d]/8192
//   K3b: M_b = Wout_bf16 @ Gt_b (single-buffer 128^2 GEMM)
//   K4 : y = x @ M_b^T + b_out (A reg-staged f32, B gload_lds, fp32 store)
//
// MFMA 16x16x32 bf16 (verified r1-13):
//   A frag: lane l holds A[row=l&15][k = ks*32 + (l>>4)*8 + e]
//   B frag: lane l holds B[col=l&15][same k]
//   C/D   : lane l reg r -> C[row=(l>>4)*4+r][col=l&15]
// LDS swizzle (8-short XOR, PMC-verified 0 conflicts):
//   stage src col pre-swizzled ((l&7)^(l>>3))*8; read col ^ ((c16&7)<<3)
// Epilogue kn/vn LDS ([64 d][128 n], 16B-granular XOR):
//   phys_short(d,n) = d*128 + ((n>>3)^(d&15))*8 + (n&7)
// k1/k4 vmcnt ledger: [4x gload_lds B] then [8x dwordx4 A(kt+1)] (order
//   pinned by sched_barrier(0)) -> vmcnt(8) drains B, keeps A in flight.
// ---------------------------------------------------------------------------

typedef __attribute__((ext_vector_type(8))) short bf16x8;
typedef __attribute__((ext_vector_type(4))) float f32x4;
typedef __attribute__((ext_vector_type(4))) unsigned short u16x4;
typedef __attribute__((ext_vector_type(4))) unsigned int u32x4;

__device__ __forceinline__ unsigned short f2bf(float f) {
  unsigned int u = __builtin_bit_cast(unsigned int, f);
  u += 0x7FFFu + ((u >> 16) & 1u);   // RNE
  return (unsigned short)(u >> 16);
}

__device__ __forceinline__ unsigned int cvt2(float lo, float hi) {
  return ((unsigned int)f2bf(hi) << 16) | (unsigned int)f2bf(lo);
}

__device__ __forceinline__ f32x4 mfma16(bf16x8 a, bf16x8 b, f32x4 c) {
  return __builtin_amdgcn_mfma_f32_16x16x32_bf16(a, b, c, 0, 0, 0);
}

__device__ __forceinline__ void gload16(const void* g, void* l) {
  __builtin_amdgcn_global_load_lds(
      (const __attribute__((address_space(1))) void*)g,
      (__attribute__((address_space(3))) void*)l, 16, 0, 0);
}

// ------------------------ K0: convert weights (merged) ----------------------
__global__ void k_cvt_w(const float* __restrict__ Wqkv,
                        const float* __restrict__ Wout,
                        unsigned short* __restrict__ Wb,
                        unsigned short* __restrict__ Wob) {
  int i = blockIdx.x * 256 + threadIdx.x;
  const float4* src;
  u16x4* dst;
  if (i < 196608) { src = (const float4*)Wqkv + i; dst = (u16x4*)Wb + i; }
  else { i -= 196608; src = (const float4*)Wout + i; dst = (u16x4*)Wob + i; }
  float4 v = *src;
  u16x4 o;
  o[0] = f2bf(v.x); o[1] = f2bf(v.y); o[2] = f2bf(v.z); o[3] = f2bf(v.w);
  *dst = o;
}

// ---------------- K1: kv GEMM (A reg-staged f32) + LN + P -------------------
// 1D grid 2048 (XCD-swizzled): wgid=(bid&7)*256+(bid>>3); rt=wgid>>3, h=wgid&7
__launch_bounds__(256, 3)
__global__ void k1_kvp(const float* __restrict__ x,
                       const unsigned short* __restrict__ wqkvb,
                       const float* __restrict__ gK, const float* __restrict__ bK,
                       const float* __restrict__ gV, const float* __restrict__ bV,
                       float* __restrict__ Ppart) {
  __shared__ __align__(16) unsigned short As[8192];   // 16 KB: A [128][64]
  __shared__ __align__(16) unsigned short Bs[8192];   // 16 KB: B [128][64]
  const int bid = (int)blockIdx.x;
  const int wgid = (bid & 7) * 256 + (bid >> 3);      // bijective (2048%8==0)
  const int rt = wgid >> 3, h = wgid & 7;
  const int tid = (int)threadIdx.x;
  const int l = tid & 63, w = tid >> 6;
  const int wr = w >> 1, wc = w & 1;
  const int g = l >> 4, c16 = l & 15;
  const int row0 = rt * 128;
  const int swz = ((l & 7) ^ (l >> 3)) * 8;           // logical col in 64-blk

  const float* gx = x + (size_t)(row0 + w * 32 + (l >> 3)) * 512 + swz;
  const int bcol = (w < 2) ? (512 + h * 64 + w * 32) : (1024 + h * 64 + (w - 2) * 32);
  const unsigned short* gsB = wqkvb + (bcol + (l >> 3)) * 512 + swz;
  unsigned short* la = As + w * 2048 + l * 8;         // + j*512 per row-slice

  f32x4 acc[4][4] = {};
  float4 pf[8];

  // prologue: A(0) f32 loads
#pragma unroll
  for (int j = 0; j < 4; ++j) {
    pf[2 * j]     = *(const float4*)(gx + j * 4096);
    pf[2 * j + 1] = *(const float4*)(gx + j * 4096 + 4);
  }

  for (int kt = 0; kt < 8; ++kt) {
    // convert + write A(kt) (compiler waits the pf loads here)
#pragma unroll
    for (int j = 0; j < 4; ++j) {
      u32x4 c;
      c[0] = cvt2(pf[2 * j].x, pf[2 * j].y);
      c[1] = cvt2(pf[2 * j].z, pf[2 * j].w);
      c[2] = cvt2(pf[2 * j + 1].x, pf[2 * j + 1].y);
      c[3] = cvt2(pf[2 * j + 1].z, pf[2 * j + 1].w);
      *(u32x4*)(la + j * 512) = c;
    }
    // stage B(kt) via global_load_lds
#pragma unroll
    for (int j = 0; j < 4; ++j)
      gload16(gsB + kt * 64 + j * 8 * 512, Bs + w * 2048 + j * 512);
    __builtin_amdgcn_sched_barrier(0);   // pin: B gloads BEFORE A prefetch
    if (kt < 7) {
      // prefetch A(kt+1) f32 -- stays in flight across the barrier
#pragma unroll
      for (int j = 0; j < 4; ++j) {
        pf[2 * j]     = *(const float4*)(gx + (kt + 1) * 64 + j * 4096);
        pf[2 * j + 1] = *(const float4*)(gx + (kt + 1) * 64 + j * 4096 + 4);
      }
      asm volatile("s_waitcnt vmcnt(8) lgkmcnt(0)" ::: "memory");
    } else {
      asm volatile("s_waitcnt vmcnt(0) lgkmcnt(0)" ::: "memory");
    }
    __builtin_amdgcn_sched_barrier(0);
    __builtin_amdgcn_s_barrier();        // tile ready
    // compute
#pragma unroll
    for (int ks = 0; ks < 2; ++ks) {
      const int kcol = (ks * 32 + g * 8) ^ ((c16 & 7) << 3);
      bf16x8 af[4], bfv[4];
#pragma unroll
      for (int mi = 0; mi < 4; ++mi)
        af[mi] = *(const bf16x8*)&As[(wr * 64 + mi * 16 + c16) * 64 + kcol];
#pragma unroll
      for (int ni = 0; ni < 4; ++ni)
        bfv[ni] = *(const bf16x8*)&Bs[(wc * 64 + ni * 16 + c16) * 64 + kcol];
#pragma unroll
      for (int mi = 0; mi < 4; ++mi)
#pragma unroll
        for (int ni = 0; ni < 4; ++ni)
          acc[mi][ni] = mfma16(af[mi], bfv[ni], acc[mi][ni]);
    }
    __builtin_amdgcn_sched_barrier(0);
    __builtin_amdgcn_s_barrier();        // LDS free for next kt's writes
  }

  // ---- per-head LayerNorm (wc=0 -> k, wc=1 -> v)
  const float* gamma = (wc == 0) ? gK : gV;
  const float* beta  = (wc == 0) ? bK : bV;
  float gm[4], bt[4];
#pragma unroll
  for (int ni = 0; ni < 4; ++ni) {
    gm[ni] = gamma[h * 64 + ni * 16 + c16];
    bt[ni] = beta[h * 64 + ni * 16 + c16];
  }
  // kn -> As ([64 d][128 n]), vn -> Bs
  unsigned short* dst = (wc == 0) ? As : Bs;
#pragma unroll
  for (int mi = 0; mi < 4; ++mi) {
    float mean4[4], rs4[4];
#pragma unroll
    for (int r = 0; r < 4; ++r) {
      float a0 = acc[mi][0][r], a1 = acc[mi][1][r];
      float a2 = acc[mi][2][r], a3 = acc[mi][3][r];
      float s1 = a0 + a1 + a2 + a3;
      float s2 = a0 * a0 + a1 * a1 + a2 * a2 + a3 * a3;
#pragma unroll
      for (int m = 1; m <= 8; m <<= 1) {   // reduce over 16-lane col group
        s1 += __shfl_xor(s1, m, 64);
        s2 += __shfl_xor(s2, m, 64);
      }
      const float mean = s1 * (1.0f / 64.0f);
      const float var = s2 * (1.0f / 64.0f) - mean * mean;
      mean4[r] = mean;
      rs4[r] = rsqrtf(var + 1e-5f);
    }
    const int n0 = wr * 64 + mi * 16 + g * 4;
#pragma unroll
    for (int ni = 0; ni < 4; ++ni) {
      u16x4 o;
#pragma unroll
      for (int r = 0; r < 4; ++r)
        o[r] = f2bf((acc[mi][ni][r] - mean4[r]) * rs4[r] * gm[ni] + bt[ni]);
      // phys8 = (n>>3) ^ (d&15); d&15 == c16
      *(u16x4*)&dst[(ni * 16 + c16) * 128 + (((n0 >> 3) ^ c16) << 3) + (n0 & 7)] = o;
    }
  }
  __syncthreads();

  // ---- P-partial: wave w covers dh rows w*16..w*16+15, all 64 dv, n=128
  f32x4 pacc[4] = {};
#pragma unroll
  for (int ks = 0; ks < 4; ++ks) {
    const int grp = ((ks * 4 + g) ^ c16) << 3;
    bf16x8 af = *(const bf16x8*)&As[(w * 16 + c16) * 128 + grp];
#pragma unroll
    for (int ni = 0; ni < 4; ++ni) {
      bf16x8 bv = *(const bf16x8*)&Bs[(ni * 16 + c16) * 128 + grp];
      pacc[ni] = mfma16(af, bv, pacc[ni]);
    }
  }
  const int bh = (rt >> 6) * 8 + h;
  float* Pp = Ppart + ((size_t)(bh * 64 + (rt & 63))) * 4096;
#pragma unroll
  for (int ni = 0; ni < 4; ++ni)
#pragma unroll
    for (int r = 0; r < 4; ++r)
      Pp[(w * 16 + g * 4 + r) * 64 + ni * 16 + c16] = pacc[ni][r];
}

// ------ K3a (fused reduce): Gt[b][d][h*64+dv] from Ppart directly -----------
// grid 32 (one block per bh), 256 threads; reduce 64 slabs -> Pl, then all 8
// d-blocks. Gt[b][d][h*64+dv] = sum_dh P[bh][dh][dv] * Wqkv[h*64+dh][d]/8192
__launch_bounds__(256)
__global__ void k3a_g(const float* __restrict__ Wqkv,
                      const float* __restrict__ Ppart,
                      unsigned short* __restrict__ Gt) {
  __shared__ float Pl[4096];
  const int bh = blockIdx.x;
  const int b = bh >> 3, h = bh & 7;
  const int t = (int)threadIdx.x;

  // reduce: thread t sums float4 lanes {t, t+256, t+512, t+768} over 64 slabs
  float4 a0 = {0, 0, 0, 0}, a1 = a0, a2 = a0, a3 = a0;
  const float* base = Ppart + (size_t)bh * 262144;
  for (int sl = 0; sl < 64; ++sl) {
    const float4* p = (const float4*)(base + sl * 4096);
    float4 v0 = p[t], v1 = p[t + 256], v2 = p[t + 512], v3 = p[t + 768];
    a0.x += v0.x; a0.y += v0.y; a0.z += v0.z; a0.w += v0.w;
    a1.x += v1.x; a1.y += v1.y; a1.z += v1.z; a1.w += v1.w;
    a2.x += v2.x; a2.y += v2.y; a2.z += v2.z; a2.w += v2.w;
    a3.x += v3.x; a3.y += v3.y; a3.z += v3.z; a3.w += v3.w;
  }
  ((float4*)Pl)[t] = a0;
  ((float4*)Pl)[t + 256] = a1;
  ((float4*)Pl)[t + 512] = a2;
  ((float4*)Pl)[t + 768] = a3;
  __syncthreads();

  const int qg = t >> 6, dl = t & 63;
  for (int dd = 0; dd < 8; ++dd) {
    const int d = dd * 64 + dl;
    float acc[16] = {};
    for (int dh = 0; dh < 64; ++dh) {
      const float wq = Wqkv[(h * 64 + dh) * 512 + d];
      const float* pr = &Pl[dh * 64 + qg * 16];
#pragma unroll
      for (int i = 0; i < 16; ++i) acc[i] += pr[i] * wq;
    }
    unsigned short* go = &Gt[(b * 512 + d) * 512 + h * 64 + qg * 16];
#pragma unroll
    for (int i = 0; i < 16; ++i) go[i] = f2bf(acc[i] * (1.0f / 8192.0f));
  }
}

// ----------------------- 128^2 single-buffer GEMM pieces --------------------
__device__ __forceinline__ void stage_tile(const unsigned short* pa,
                                           const unsigned short* pb,
                                           unsigned short* As, unsigned short* Bs,
                                           int w) {
#pragma unroll
  for (int j = 0; j < 4; ++j) {
    gload16(pa + j * 8 * 512, As + w * 2048 + j * 512);
    gload16(pb + j * 8 * 512, Bs + w * 2048 + j * 512);
  }
}

__device__ __forceinline__ void compute_tile(const unsigned short* As,
                                             const unsigned short* Bs,
                                             int wr, int wc, int g, int c16,
                                             f32x4 acc[4][4]) {
#pragma unroll
  for (int ks = 0; ks < 2; ++ks) {
    const int kcol = (ks * 32 + g * 8) ^ ((c16 & 7) << 3);
    bf16x8 af[4], bfv[4];
#pragma unroll
    for (int mi = 0; mi < 4; ++mi)
      af[mi] = *(const bf16x8*)&As[(wr * 64 + mi * 16 + c16) * 64 + kcol];
#pragma unroll
    for (int ni = 0; ni < 4; ++ni)
      bfv[ni] = *(const bf16x8*)&Bs[(wc * 64 + ni * 16 + c16) * 64 + kcol];
#pragma unroll
    for (int mi = 0; mi < 4; ++mi)
#pragma unroll
      for (int ni = 0; ni < 4; ++ni)
        acc[mi][ni] = mfma16(af[mi], bfv[ni], acc[mi][ni]);
  }
}

// ----------- K3b: M_b[d'][d] = sum_e Wout[d'][e] * Gt_b[d][e] ---------------
__launch_bounds__(256)
__global__ void k3b_m(const unsigned short* __restrict__ wob,
                      const unsigned short* __restrict__ Gt,
                      unsigned short* __restrict__ Mb) {
  __shared__ __align__(16) unsigned short As[8192];
  __shared__ __align__(16) unsigned short Bs[8192];
  const int rt = blockIdx.x, ct = blockIdx.y, b = blockIdx.z;
  const int tid = (int)threadIdx.x;
  const int l = tid & 63, w = tid >> 6;
  const int wr = w >> 1, wc = w & 1;
  const int g = l >> 4, c16 = l & 15;
  const int row0 = rt * 128, col0 = ct * 128;
  const int swz = ((l & 7) ^ (l >> 3)) * 8;

  const unsigned short* gsA = wob + (row0 + w * 32 + (l >> 3)) * 512 + swz;
  const unsigned short* gsB = Gt + b * 262144 + (col0 + w * 32 + (l >> 3)) * 512 + swz;

  f32x4 acc[4][4] = {};
  for (int kt = 0; kt < 8; ++kt) {
    stage_tile(gsA + kt * 64, gsB + kt * 64, As, Bs, w);
    __syncthreads();
    compute_tile(As, Bs, wr, wc, g, c16, acc);
    __syncthreads();
  }

#pragma unroll
  for (int mi = 0; mi < 4; ++mi)
#pragma unroll
    for (int ni = 0; ni < 4; ++ni) {
      const int colg = col0 + wc * 64 + ni * 16 + c16;
#pragma unroll
      for (int r = 0; r < 4; ++r) {
        const int rowg = row0 + wr * 64 + mi * 16 + g * 4 + r;
        Mb[(b * 512 + rowg) * 512 + colg] = f2bf(acc[mi][ni][r]);
      }
    }
}

// ---------------- K4: y = x @ M_b^T + b_out (A reg-staged f32) --------------
// 1D grid 1024 (XCD-swizzled): wgid=(bid&7)*128+(bid>>3); rt=wgid>>2, ct=wgid&3
__launch_bounds__(256, 3)
__global__ void k4_final(const float* __restrict__ x,
                         const unsigned short* __restrict__ Mb,
                         const float* __restrict__ bout,
                         float* __restrict__ y) {
  __shared__ __align__(16) unsigned short As[8192];
  __shared__ __align__(16) unsigned short Bs[8192];
  const int bid = (int)blockIdx.x;
  const int wgid = (bid & 7) * 128 + (bid >> 3);      // bijective (1024%8==0)
  const int rt = wgid >> 2, ct = wgid & 3;
  const int tid = (int)threadIdx.x;
  const int l = tid & 63, w = tid >> 6;
  const int wr = w >> 1, wc = w & 1;
  const int g = l >> 4, c16 = l & 15;
  const int row0 = rt * 128, col0 = ct * 128;
  const int bb = row0 >> 13;
  const int swz = ((l & 7) ^ (l >> 3)) * 8;

  const float* gx = x + (size_t)(row0 + w * 32 + (l >> 3)) * 512 + swz;
  const unsigned short* gsB =
      Mb + (size_t)bb * 262144 + (col0 + w * 32 + (l >> 3)) * 512 + swz;
  unsigned short* la = As + w * 2048 + l * 8;

  f32x4 acc[4][4] = {};
  float4 pf[8];
#pragma unroll
  for (int j = 0; j < 4; ++j) {
    pf[2 * j]     = *(const float4*)(gx + j * 4096);
    pf[2 * j + 1] = *(const float4*)(gx + j * 4096 + 4);
  }

  for (int kt = 0; kt < 8; ++kt) {
#pragma unroll
    for (int j = 0; j < 4; ++j) {
      u32x4 c;
      c[0] = cvt2(pf[2 * j].x, pf[2 * j].y);
      c[1] = cvt2(pf[2 * j].z, pf[2 * j].w);
      c[2] = cvt2(pf[2 * j + 1].x, pf[2 * j + 1].y);
      c[3] = cvt2(pf[2 * j + 1].z, pf[2 * j + 1].w);
      *(u32x4*)(la + j * 512) = c;
    }
#pragma unroll
    for (int j = 0; j < 4; ++j)
      gload16(gsB + kt * 64 + j * 8 * 512, Bs + w * 2048 + j * 512);
    __builtin_amdgcn_sched_barrier(0);
    if (kt < 7) {
#pragma unroll
      for (int j = 0; j < 4; ++j) {
        pf[2 * j]     = *(const float4*)(gx + (kt + 1) * 64 + j * 4096);
        pf[2 * j + 1] = *(const float4*)(gx + (kt + 1) * 64 + j * 4096 + 4);
      }
      asm volatile("s_waitcnt vmcnt(8) lgkmcnt(0)" ::: "memory");
    } else {
      asm volatile("s_waitcnt vmcnt(0) lgkmcnt(0)" ::: "memory");
    }
    __builtin_amdgcn_sched_barrier(0);
    __builtin_amdgcn_s_barrier();
#pragma unroll
    for (int ks = 0; ks < 2; ++ks) {
      const int kcol = (ks * 32 + g * 8) ^ ((c16 & 7) << 3);
      bf16x8 af[4], bfv[4];
#pragma unroll
      for (int mi = 0; mi < 4; ++mi)
        af[mi] = *(const bf16x8*)&As[(wr * 64 + mi * 16 + c16) * 64 + kcol];
#pragma unroll
      for (int ni = 0; ni < 4; ++ni)
        bfv[ni] = *(const bf16x8*)&Bs[(wc * 64 + ni * 16 + c16) * 64 + kcol];
#pragma unroll
      for (int mi = 0; mi < 4; ++mi)
#pragma unroll
        for (int ni = 0; ni < 4; ++ni)
          acc[mi][ni] = mfma16(af[mi], bfv[ni], acc[mi][ni]);
    }
    __builtin_amdgcn_sched_barrier(0);
    __builtin_amdgcn_s_barrier();
  }

  float bo[4];
#pragma unroll
  for (int ni = 0; ni < 4; ++ni)
    bo[ni] = bout[col0 + wc * 64 + ni * 16 + c16];
#pragma unroll
  for (int mi = 0; mi < 4; ++mi)
#pragma unroll
    for (int ni = 0; ni < 4; ++ni) {
      const int colg = col0 + wc * 64 + ni * 16 + c16;
#pragma unroll
      for (int r = 0; r < 4; ++r) {
        const int rowg = row0 + wr * 64 + mi * 16 + g * 4 + r;
        y[rowg * 512 + colg] = acc[mi][ni][r] + bo[ni];
      }
    }
}

// ---------------------------------------------------------------------------
extern "C" void kernel_launch(void* const* d_in, const int* in_sizes, int n_in,
                              void* d_out, int out_size, void* d_ws, size_t ws_size,
                              hipStream_t stream) {
  (void)in_sizes; (void)n_in; (void)out_size; (void)ws_size;
  const float* x    = (const float*)d_in[0];
  const float* Wqkv = (const float*)d_in[1];
  const float* gK   = (const float*)d_in[2];
  const float* bK   = (const float*)d_in[3];
  const float* gV   = (const float*)d_in[4];
  const float* bV   = (const float*)d_in[5];
  const float* Wout = (const float*)d_in[6];
  const float* bout = (const float*)d_in[7];
  float* y = (float*)d_out;

  // workspace carve (~40 MB)
  char* w = (char*)d_ws;
  unsigned short* Wb    = (unsigned short*)(w);             //  1,572,864
  unsigned short* Wob   = (unsigned short*)(w + 1572864);   //    524,288
  unsigned short* Gt    = (unsigned short*)(w + 2097152);   //  2,097,152
  unsigned short* Mb    = (unsigned short*)(w + 4194304);   //  2,097,152
  float*          Ppart = (float*)         (w + 6291456);   // 33,554,432

  k_cvt_w<<<1024, 256, 0, stream>>>(Wqkv, Wout, Wb, Wob);

  k1_kvp<<<2048, 256, 0, stream>>>(x, Wb, gK, bK, gV, bV, Ppart);
  k3a_g<<<32, 256, 0, stream>>>(Wqkv, Ppart, Gt);
  k3b_m<<<dim3(4, 4, 4), 256, 0, stream>>>(Wob, Gt, Mb);
  k4_final<<<1024, 256, 0, stream>>>(x, Mb, bout, y);
}

// Round 15
// 125.987 us; speedup vs baseline: 1.5593x; 1.3820x over previous
//
#include <hip/hip_runtime.h>

// ---------------------------------------------------------------------------
// GalerkinAttention on MI355X (gfx950), round 15 = r10 champion (127.3us)
// with two traffic-only deltas:
//   (1) Ppart stored as bf16 (32->16 MB; numerically free: partials feed a
//       64-way sum whose product term is ~1e-9 absolute in the output)
//   (2) r14's 32-block fused k3a REVERTED to r10's parallel
//       preduce(512 blocks) + k3a(256 blocks) pair (fusion was -45us).
// Everything else byte-identical to r10.
//
// Shapes: B=4, N=8192, D=512, H=8, Dh=64. Algebra: y = x @ M_b^T + b_out,
//   M_b[d'][d] = sum_h W_out[d',h-blk] . P_bh . W_q[h-blk,d] / n
//
// Pipeline:
//   K0 : convert W_qkv, W_out to bf16 (merged)
//   K1 : per (128-row-tile, head): kv = x @ W^T; A reg-staged from f32
//        (1-deep prefetch), B via global_load_lds; 32KB LDS, 2 barriers/kt;
//        epilogue: in-register LN -> kn/vn to LDS (16B-XOR transpose) ->
//        P-partial MFMA -> bf16 partial stores to Ppart (no atomics)
//   KR : P[bh] = sum_slab Ppart (512 blocks, f32 accum)
//   K3a: Gt[b][d][h*64+dv] = sum_dh P[bh][dh][dv] * Wqkv[h*64+dh][d]/8192
//   K3b: M_b = Wout_bf16 @ Gt_b (single-buffer 128^2 GEMM)
//   K4 : y = x @ M_b^T + b_out (A reg-staged f32, B gload_lds, fp32 store)
//
// MFMA 16x16x32 bf16 (verified r1-14):
//   A frag: lane l holds A[row=l&15][k = ks*32 + (l>>4)*8 + e]
//   B frag: lane l holds B[col=l&15][same k]
//   C/D   : lane l reg r -> C[row=(l>>4)*4+r][col=l&15]
// LDS swizzle (8-short XOR, PMC-verified 0 conflicts):
//   stage src col pre-swizzled ((l&7)^(l>>3))*8; read col ^ ((c16&7)<<3)
// Epilogue kn/vn LDS ([64 d][128 n], 16B-granular XOR):
//   phys_short(d,n) = d*128 + ((n>>3)^(d&15))*8 + (n&7)
// k1/k4 vmcnt ledger: [4x gload_lds B] then [8x dwordx4 A(kt+1)] (order
//   pinned by sched_barrier(0)) -> vmcnt(8) drains B, keeps A in flight.
// ---------------------------------------------------------------------------

typedef __attribute__((ext_vector_type(8))) short bf16x8;
typedef __attribute__((ext_vector_type(4))) float f32x4;
typedef __attribute__((ext_vector_type(4))) unsigned short u16x4;
typedef __attribute__((ext_vector_type(4))) unsigned int u32x4;

__device__ __forceinline__ unsigned short f2bf(float f) {
  unsigned int u = __builtin_bit_cast(unsigned int, f);
  u += 0x7FFFu + ((u >> 16) & 1u);   // RNE
  return (unsigned short)(u >> 16);
}

__device__ __forceinline__ float bf2f(unsigned short h) {
  unsigned int u = ((unsigned int)h) << 16;
  return __builtin_bit_cast(float, u);
}

__device__ __forceinline__ unsigned int cvt2(float lo, float hi) {
  return ((unsigned int)f2bf(hi) << 16) | (unsigned int)f2bf(lo);
}

__device__ __forceinline__ f32x4 mfma16(bf16x8 a, bf16x8 b, f32x4 c) {
  return __builtin_amdgcn_mfma_f32_16x16x32_bf16(a, b, c, 0, 0, 0);
}

__device__ __forceinline__ void gload16(const void* g, void* l) {
  __builtin_amdgcn_global_load_lds(
      (const __attribute__((address_space(1))) void*)g,
      (__attribute__((address_space(3))) void*)l, 16, 0, 0);
}

// ------------------------ K0: convert weights (merged) ----------------------
__global__ void k_cvt_w(const float* __restrict__ Wqkv,
                        const float* __restrict__ Wout,
                        unsigned short* __restrict__ Wb,
                        unsigned short* __restrict__ Wob) {
  int i = blockIdx.x * 256 + threadIdx.x;
  const float4* src;
  u16x4* dst;
  if (i < 196608) { src = (const float4*)Wqkv + i; dst = (u16x4*)Wb + i; }
  else { i -= 196608; src = (const float4*)Wout + i; dst = (u16x4*)Wob + i; }
  float4 v = *src;
  u16x4 o;
  o[0] = f2bf(v.x); o[1] = f2bf(v.y); o[2] = f2bf(v.z); o[3] = f2bf(v.w);
  *dst = o;
}

// ---------------- K1: kv GEMM (A reg-staged f32) + LN + P -------------------
// 1D grid 2048 (XCD-swizzled): wgid=(bid&7)*256+(bid>>3); rt=wgid>>3, h=wgid&7
__launch_bounds__(256, 3)
__global__ void k1_kvp(const float* __restrict__ x,
                       const unsigned short* __restrict__ wqkvb,
                       const float* __restrict__ gK, const float* __restrict__ bK,
                       const float* __restrict__ gV, const float* __restrict__ bV,
                       unsigned short* __restrict__ Ppart) {
  __shared__ __align__(16) unsigned short As[8192];   // 16 KB: A [128][64]
  __shared__ __align__(16) unsigned short Bs[8192];   // 16 KB: B [128][64]
  const int bid = (int)blockIdx.x;
  const int wgid = (bid & 7) * 256 + (bid >> 3);      // bijective (2048%8==0)
  const int rt = wgid >> 3, h = wgid & 7;
  const int tid = (int)threadIdx.x;
  const int l = tid & 63, w = tid >> 6;
  const int wr = w >> 1, wc = w & 1;
  const int g = l >> 4, c16 = l & 15;
  const int row0 = rt * 128;
  const int swz = ((l & 7) ^ (l >> 3)) * 8;           // logical col in 64-blk

  const float* gx = x + (size_t)(row0 + w * 32 + (l >> 3)) * 512 + swz;
  const int bcol = (w < 2) ? (512 + h * 64 + w * 32) : (1024 + h * 64 + (w - 2) * 32);
  const unsigned short* gsB = wqkvb + (bcol + (l >> 3)) * 512 + swz;
  unsigned short* la = As + w * 2048 + l * 8;         // + j*512 per row-slice

  f32x4 acc[4][4] = {};
  float4 pf[8];

  // prologue: A(0) f32 loads
#pragma unroll
  for (int j = 0; j < 4; ++j) {
    pf[2 * j]     = *(const float4*)(gx + j * 4096);
    pf[2 * j + 1] = *(const float4*)(gx + j * 4096 + 4);
  }

  for (int kt = 0; kt < 8; ++kt) {
    // convert + write A(kt) (compiler waits the pf loads here)
#pragma unroll
    for (int j = 0; j < 4; ++j) {
      u32x4 c;
      c[0] = cvt2(pf[2 * j].x, pf[2 * j].y);
      c[1] = cvt2(pf[2 * j].z, pf[2 * j].w);
      c[2] = cvt2(pf[2 * j + 1].x, pf[2 * j + 1].y);
      c[3] = cvt2(pf[2 * j + 1].z, pf[2 * j + 1].w);
      *(u32x4*)(la + j * 512) = c;
    }
    // stage B(kt) via global_load_lds
#pragma unroll
    for (int j = 0; j < 4; ++j)
      gload16(gsB + kt * 64 + j * 8 * 512, Bs + w * 2048 + j * 512);
    __builtin_amdgcn_sched_barrier(0);   // pin: B gloads BEFORE A prefetch
    if (kt < 7) {
      // prefetch A(kt+1) f32 -- stays in flight across the barrier
#pragma unroll
      for (int j = 0; j < 4; ++j) {
        pf[2 * j]     = *(const float4*)(gx + (kt + 1) * 64 + j * 4096);
        pf[2 * j + 1] = *(const float4*)(gx + (kt + 1) * 64 + j * 4096 + 4);
      }
      asm volatile("s_waitcnt vmcnt(8) lgkmcnt(0)" ::: "memory");
    } else {
      asm volatile("s_waitcnt vmcnt(0) lgkmcnt(0)" ::: "memory");
    }
    __builtin_amdgcn_sched_barrier(0);
    __builtin_amdgcn_s_barrier();        // tile ready
    // compute
#pragma unroll
    for (int ks = 0; ks < 2; ++ks) {
      const int kcol = (ks * 32 + g * 8) ^ ((c16 & 7) << 3);
      bf16x8 af[4], bfv[4];
#pragma unroll
      for (int mi = 0; mi < 4; ++mi)
        af[mi] = *(const bf16x8*)&As[(wr * 64 + mi * 16 + c16) * 64 + kcol];
#pragma unroll
      for (int ni = 0; ni < 4; ++ni)
        bfv[ni] = *(const bf16x8*)&Bs[(wc * 64 + ni * 16 + c16) * 64 + kcol];
#pragma unroll
      for (int mi = 0; mi < 4; ++mi)
#pragma unroll
        for (int ni = 0; ni < 4; ++ni)
          acc[mi][ni] = mfma16(af[mi], bfv[ni], acc[mi][ni]);
    }
    __builtin_amdgcn_sched_barrier(0);
    __builtin_amdgcn_s_barrier();        // LDS free for next kt's writes
  }

  // ---- per-head LayerNorm (wc=0 -> k, wc=1 -> v)
  const float* gamma = (wc == 0) ? gK : gV;
  const float* beta  = (wc == 0) ? bK : bV;
  float gm[4], bt[4];
#pragma unroll
  for (int ni = 0; ni < 4; ++ni) {
    gm[ni] = gamma[h * 64 + ni * 16 + c16];
    bt[ni] = beta[h * 64 + ni * 16 + c16];
  }
  // kn -> As ([64 d][128 n]), vn -> Bs
  unsigned short* dst = (wc == 0) ? As : Bs;
#pragma unroll
  for (int mi = 0; mi < 4; ++mi) {
    float mean4[4], rs4[4];
#pragma unroll
    for (int r = 0; r < 4; ++r) {
      float a0 = acc[mi][0][r], a1 = acc[mi][1][r];
      float a2 = acc[mi][2][r], a3 = acc[mi][3][r];
      float s1 = a0 + a1 + a2 + a3;
      float s2 = a0 * a0 + a1 * a1 + a2 * a2 + a3 * a3;
#pragma unroll
      for (int m = 1; m <= 8; m <<= 1) {   // reduce over 16-lane col group
        s1 += __shfl_xor(s1, m, 64);
        s2 += __shfl_xor(s2, m, 64);
      }
      const float mean = s1 * (1.0f / 64.0f);
      const float var = s2 * (1.0f / 64.0f) - mean * mean;
      mean4[r] = mean;
      rs4[r] = rsqrtf(var + 1e-5f);
    }
    const int n0 = wr * 64 + mi * 16 + g * 4;
#pragma unroll
    for (int ni = 0; ni < 4; ++ni) {
      u16x4 o;
#pragma unroll
      for (int r = 0; r < 4; ++r)
        o[r] = f2bf((acc[mi][ni][r] - mean4[r]) * rs4[r] * gm[ni] + bt[ni]);
      // phys8 = (n>>3) ^ (d&15); d&15 == c16
      *(u16x4*)&dst[(ni * 16 + c16) * 128 + (((n0 >> 3) ^ c16) << 3) + (n0 & 7)] = o;
    }
  }
  __syncthreads();

  // ---- P-partial: wave w covers dh rows w*16..w*16+15, all 64 dv, n=128
  f32x4 pacc[4] = {};
#pragma unroll
  for (int ks = 0; ks < 4; ++ks) {
    const int grp = ((ks * 4 + g) ^ c16) << 3;
    bf16x8 af = *(const bf16x8*)&As[(w * 16 + c16) * 128 + grp];
#pragma unroll
    for (int ni = 0; ni < 4; ++ni) {
      bf16x8 bv = *(const bf16x8*)&Bs[(ni * 16 + c16) * 128 + grp];
      pacc[ni] = mfma16(af, bv, pacc[ni]);
    }
  }
  // bf16 partial stores: Ppart[bh][slab][dh][dv], slab = rt & 63
  const int bh = (rt >> 6) * 8 + h;
  unsigned short* Pp = Ppart + ((size_t)(bh * 64 + (rt & 63))) * 4096;
#pragma unroll
  for (int ni = 0; ni < 4; ++ni)
#pragma unroll
    for (int r = 0; r < 4; ++r)
      Pp[(w * 16 + g * 4 + r) * 64 + ni * 16 + c16] = f2bf(pacc[ni][r]);
}

// ---------------- KR: P[bh] = sum over 64 slabs of Ppart (bf16) -------------
// grid (32, 16), 256 threads: each thread sums one P element over 64 slabs
__launch_bounds__(256)
__global__ void k_preduce(const unsigned short* __restrict__ Ppart,
                          float* __restrict__ P) {
  const int bh = blockIdx.x;
  const int e = blockIdx.y * 256 + threadIdx.x;
  const unsigned short* src = Ppart + (size_t)bh * 64 * 4096 + e;
  float s = 0.f;
#pragma unroll 8
  for (int sl = 0; sl < 64; ++sl) s += bf2f(src[sl * 4096]);
  P[bh * 4096 + e] = s;
}

// ------------- K3a: Gt[b][d][h*64+dv] = sum_dh P[bh][dh][dv]*Wq[h*64+dh][d]/n
__launch_bounds__(256)
__global__ void k3a_g(const float* __restrict__ Wqkv,
                      const float* __restrict__ P,
                      unsigned short* __restrict__ Gt) {
  __shared__ float Pl[64 * 64];
  const int bh = blockIdx.x, dd = blockIdx.y;
  const int b = bh >> 3, h = bh & 7;
  const int t = (int)threadIdx.x;
  for (int i = t; i < 1024; i += 256)
    ((float4*)Pl)[i] = ((const float4*)(P + bh * 4096))[i];
  __syncthreads();

  const int qg = t >> 6, dl = t & 63;
  const int d = dd * 64 + dl;
  float acc[16] = {};
  for (int dh = 0; dh < 64; ++dh) {
    const float wq = Wqkv[(h * 64 + dh) * 512 + d];
    const float* pr = &Pl[dh * 64 + qg * 16];
#pragma unroll
    for (int i = 0; i < 16; ++i) acc[i] += pr[i] * wq;
  }
  unsigned short* go = &Gt[(b * 512 + d) * 512 + h * 64 + qg * 16];
#pragma unroll
  for (int i = 0; i < 16; ++i) go[i] = f2bf(acc[i] * (1.0f / 8192.0f));
}

// ----------------------- 128^2 single-buffer GEMM pieces --------------------
__device__ __forceinline__ void stage_tile(const unsigned short* pa,
                                           const unsigned short* pb,
                                           unsigned short* As, unsigned short* Bs,
                                           int w) {
#pragma unroll
  for (int j = 0; j < 4; ++j) {
    gload16(pa + j * 8 * 512, As + w * 2048 + j * 512);
    gload16(pb + j * 8 * 512, Bs + w * 2048 + j * 512);
  }
}

__device__ __forceinline__ void compute_tile(const unsigned short* As,
                                             const unsigned short* Bs,
                                             int wr, int wc, int g, int c16,
                                             f32x4 acc[4][4]) {
#pragma unroll
  for (int ks = 0; ks < 2; ++ks) {
    const int kcol = (ks * 32 + g * 8) ^ ((c16 & 7) << 3);
    bf16x8 af[4], bfv[4];
#pragma unroll
    for (int mi = 0; mi < 4; ++mi)
      af[mi] = *(const bf16x8*)&As[(wr * 64 + mi * 16 + c16) * 64 + kcol];
#pragma unroll
    for (int ni = 0; ni < 4; ++ni)
      bfv[ni] = *(const bf16x8*)&Bs[(wc * 64 + ni * 16 + c16) * 64 + kcol];
#pragma unroll
    for (int mi = 0; mi < 4; ++mi)
#pragma unroll
      for (int ni = 0; ni < 4; ++ni)
        acc[mi][ni] = mfma16(af[mi], bfv[ni], acc[mi][ni]);
  }
}

// ----------- K3b: M_b[d'][d] = sum_e Wout[d'][e] * Gt_b[d][e] ---------------
__launch_bounds__(256)
__global__ void k3b_m(const unsigned short* __restrict__ wob,
                      const unsigned short* __restrict__ Gt,
                      unsigned short* __restrict__ Mb) {
  __shared__ __align__(16) unsigned short As[8192];
  __shared__ __align__(16) unsigned short Bs[8192];
  const int rt = blockIdx.x, ct = blockIdx.y, b = blockIdx.z;
  const int tid = (int)threadIdx.x;
  const int l = tid & 63, w = tid >> 6;
  const int wr = w >> 1, wc = w & 1;
  const int g = l >> 4, c16 = l & 15;
  const int row0 = rt * 128, col0 = ct * 128;
  const int swz = ((l & 7) ^ (l >> 3)) * 8;

  const unsigned short* gsA = wob + (row0 + w * 32 + (l >> 3)) * 512 + swz;
  const unsigned short* gsB = Gt + b * 262144 + (col0 + w * 32 + (l >> 3)) * 512 + swz;

  f32x4 acc[4][4] = {};
  for (int kt = 0; kt < 8; ++kt) {
    stage_tile(gsA + kt * 64, gsB + kt * 64, As, Bs, w);
    __syncthreads();
    compute_tile(As, Bs, wr, wc, g, c16, acc);
    __syncthreads();
  }

#pragma unroll
  for (int mi = 0; mi < 4; ++mi)
#pragma unroll
    for (int ni = 0; ni < 4; ++ni) {
      const int colg = col0 + wc * 64 + ni * 16 + c16;
#pragma unroll
      for (int r = 0; r < 4; ++r) {
        const int rowg = row0 + wr * 64 + mi * 16 + g * 4 + r;
        Mb[(b * 512 + rowg) * 512 + colg] = f2bf(acc[mi][ni][r]);
      }
    }
}

// ---------------- K4: y = x @ M_b^T + b_out (A reg-staged f32) --------------
// 1D grid 1024 (XCD-swizzled): wgid=(bid&7)*128+(bid>>3); rt=wgid>>2, ct=wgid&3
__launch_bounds__(256, 3)
__global__ void k4_final(const float* __restrict__ x,
                         const unsigned short* __restrict__ Mb,
                         const float* __restrict__ bout,
                         float* __restrict__ y) {
  __shared__ __align__(16) unsigned short As[8192];
  __shared__ __align__(16) unsigned short Bs[8192];
  const int bid = (int)blockIdx.x;
  const int wgid = (bid & 7) * 128 + (bid >> 3);      // bijective (1024%8==0)
  const int rt = wgid >> 2, ct = wgid & 3;
  const int tid = (int)threadIdx.x;
  const int l = tid & 63, w = tid >> 6;
  const int wr = w >> 1, wc = w & 1;
  const int g = l >> 4, c16 = l & 15;
  const int row0 = rt * 128, col0 = ct * 128;
  const int bb = row0 >> 13;
  const int swz = ((l & 7) ^ (l >> 3)) * 8;

  const float* gx = x + (size_t)(row0 + w * 32 + (l >> 3)) * 512 + swz;
  const unsigned short* gsB =
      Mb + (size_t)bb * 262144 + (col0 + w * 32 + (l >> 3)) * 512 + swz;
  unsigned short* la = As + w * 2048 + l * 8;

  f32x4 acc[4][4] = {};
  float4 pf[8];
#pragma unroll
  for (int j = 0; j < 4; ++j) {
    pf[2 * j]     = *(const float4*)(gx + j * 4096);
    pf[2 * j + 1] = *(const float4*)(gx + j * 4096 + 4);
  }

  for (int kt = 0; kt < 8; ++kt) {
#pragma unroll
    for (int j = 0; j < 4; ++j) {
      u32x4 c;
      c[0] = cvt2(pf[2 * j].x, pf[2 * j].y);
      c[1] = cvt2(pf[2 * j].z, pf[2 * j].w);
      c[2] = cvt2(pf[2 * j + 1].x, pf[2 * j + 1].y);
      c[3] = cvt2(pf[2 * j + 1].z, pf[2 * j + 1].w);
      *(u32x4*)(la + j * 512) = c;
    }
#pragma unroll
    for (int j = 0; j < 4; ++j)
      gload16(gsB + kt * 64 + j * 8 * 512, Bs + w * 2048 + j * 512);
    __builtin_amdgcn_sched_barrier(0);
    if (kt < 7) {
#pragma unroll
      for (int j = 0; j < 4; ++j) {
        pf[2 * j]     = *(const float4*)(gx + (kt + 1) * 64 + j * 4096);
        pf[2 * j + 1] = *(const float4*)(gx + (kt + 1) * 64 + j * 4096 + 4);
      }
      asm volatile("s_waitcnt vmcnt(8) lgkmcnt(0)" ::: "memory");
    } else {
      asm volatile("s_waitcnt vmcnt(0) lgkmcnt(0)" ::: "memory");
    }
    __builtin_amdgcn_sched_barrier(0);
    __builtin_amdgcn_s_barrier();
#pragma unroll
    for (int ks = 0; ks < 2; ++ks) {
      const int kcol = (ks * 32 + g * 8) ^ ((c16 & 7) << 3);
      bf16x8 af[4], bfv[4];
#pragma unroll
      for (int mi = 0; mi < 4; ++mi)
        af[mi] = *(const bf16x8*)&As[(wr * 64 + mi * 16 + c16) * 64 + kcol];
#pragma unroll
      for (int ni = 0; ni < 4; ++ni)
        bfv[ni] = *(const bf16x8*)&Bs[(wc * 64 + ni * 16 + c16) * 64 + kcol];
#pragma unroll
      for (int mi = 0; mi < 4; ++mi)
#pragma unroll
        for (int ni = 0; ni < 4; ++ni)
          acc[mi][ni] = mfma16(af[mi], bfv[ni], acc[mi][ni]);
    }
    __builtin_amdgcn_sched_barrier(0);
    __builtin_amdgcn_s_barrier();
  }

  float bo[4];
#pragma unroll
  for (int ni = 0; ni < 4; ++ni)
    bo[ni] = bout[col0 + wc * 64 + ni * 16 + c16];
#pragma unroll
  for (int mi = 0; mi < 4; ++mi)
#pragma unroll
    for (int ni = 0; ni < 4; ++ni) {
      const int colg = col0 + wc * 64 + ni * 16 + c16;
#pragma unroll
      for (int r = 0; r < 4; ++r) {
        const int rowg = row0 + wr * 64 + mi * 16 + g * 4 + r;
        y[rowg * 512 + colg] = acc[mi][ni][r] + bo[ni];
      }
    }
}

// ---------------------------------------------------------------------------
extern "C" void kernel_launch(void* const* d_in, const int* in_sizes, int n_in,
                              void* d_out, int out_size, void* d_ws, size_t ws_size,
                              hipStream_t stream) {
  (void)in_sizes; (void)n_in; (void)out_size; (void)ws_size;
  const float* x    = (const float*)d_in[0];
  const float* Wqkv = (const float*)d_in[1];
  const float* gK   = (const float*)d_in[2];
  const float* bK   = (const float*)d_in[3];
  const float* gV   = (const float*)d_in[4];
  const float* bV   = (const float*)d_in[5];
  const float* Wout = (const float*)d_in[6];
  const float* bout = (const float*)d_in[7];
  float* y = (float*)d_out;

  // workspace carve (~23 MB)
  char* w = (char*)d_ws;
  unsigned short* Wb    = (unsigned short*)(w);             //  1,572,864
  unsigned short* Wob   = (unsigned short*)(w + 1572864);   //    524,288
  float*          P     = (float*)         (w + 2097152);   //    524,288
  unsigned short* Gt    = (unsigned short*)(w + 2621440);   //  2,097,152
  unsigned short* Mb    = (unsigned short*)(w + 4718592);   //  2,097,152
  unsigned short* Ppart = (unsigned short*)(w + 6815744);   // 16,777,216

  k_cvt_w<<<1024, 256, 0, stream>>>(Wqkv, Wout, Wb, Wob);

  k1_kvp<<<2048, 256, 0, stream>>>(x, Wb, gK, bK, gV, bV, Ppart);
  k_preduce<<<dim3(32, 16), 256, 0, stream>>>(Ppart, P);
  k3a_g<<<dim3(32, 8), 256, 0, stream>>>(Wqkv, P, Gt);
  k3b_m<<<dim3(4, 4, 4), 256, 0, stream>>>(Wob, Gt, Mb);
  k4_final<<<1024, 256, 0, stream>>>(x, Mb, bout, y);
}